// Round 14
// baseline (213.260 us; speedup 1.0000x reference)
//
#include <hip/hip_runtime.h>

#define HID   32
#define INCH  128
#define OUTD  8
#define BATCH 512
#define TLEN  512
#define NGRP  16                 // 512 batches / 32 per group
#define NCHK  32                 // 32 chunks x 16 timesteps
#define ITEMS 2048               // 32 c x 16 g x 4 sub
#define XP_BYTES (16u * 1024u * 1024u)   // f16 xp: 16*512*64*32 B

typedef __attribute__((ext_vector_type(2)))  int    i32x2;
typedef __attribute__((ext_vector_type(4)))  int    i32x4;
typedef __attribute__((ext_vector_type(8)))  short  short8_t;
typedef __attribute__((ext_vector_type(16))) float  f32x16_t;
typedef __attribute__((ext_vector_type(8)))  _Float16 half8_t;
typedef __attribute__((ext_vector_type(2)))  _Float16 h2v;

// Symmetric permlane32 idiom (HW-verified rounds 6/8): r[0]+r[1] = own+partner
// for swap32v(x,x), under ANY of the possible vdst/vsrc pairing semantics.
__device__ __forceinline__ i32x2 swap32v(int a, int b)
{
#if __has_builtin(__builtin_amdgcn_permlane32_swap)
    return __builtin_amdgcn_permlane32_swap(a, b, false, false);
#else
    const int lane = threadIdx.x & 63;
    int as = __shfl_xor(a, 32, 64), bs = __shfl_xor(b, 32, 64);
    i32x2 r;
    r[0] = (lane < 32) ? bs : a;
    r[1] = (lane < 32) ? b  : as;
    return r;
#endif
}

__device__ __forceinline__ float swap32_add(float p)
{
    i32x2 r = swap32v(__float_as_int(p), __float_as_int(p));
    return __int_as_float(r[0]) + __int_as_float(r[1]);
}

// Broadcast half-`from`'s x to all lanes (same batch column b = lane&31):
// z = x on half `from`, 0 elsewhere; own+partner sum then has one zero term.
// Built ONLY from the verified symmetric idiom -> semantics-proof.
__device__ __forceinline__ int bhalf(int x, int p, int from)
{
    const int z = (p == from) ? x : 0;
    i32x2 r = swap32v(z, z);
    return r[0] + r[1];
}

// Split fp32 -> bf16 hi (bit-truncate) + bf16 lo (truncated residual).
__device__ __forceinline__ void split8(const float4 f0, const float4 f1,
                                       short8_t* hi, short8_t* lo)
{
    float x[8] = {f0.x, f0.y, f0.z, f0.w, f1.x, f1.y, f1.z, f1.w};
    short8_t h, l;
    #pragma unroll
    for (int e = 0; e < 8; ++e) {
        const unsigned u  = __float_as_uint(x[e]);
        const unsigned hb = u & 0xFFFF0000u;
        h[e] = (short)(u >> 16);
        const float r = x[e] - __uint_as_float(hb);
        l[e] = (short)(__float_as_uint(r) >> 16);
    }
    *hi = h; *lo = l;
}

// pack two f32 -> f16 RNE packed word (proj side, off critical path)
__device__ __forceinline__ unsigned pk2_rn(float a, float b)
{
    unsigned short ha = __builtin_bit_cast(unsigned short, (_Float16)a);
    unsigned short hb = __builtin_bit_cast(unsigned short, (_Float16)b);
    return (unsigned)ha | ((unsigned)hb << 16);
}

// relu in f32 (commutes with monotone cvt), then packed f16 convert
__device__ __forceinline__ unsigned cvt_relu_pk(float a, float b)
{
    const float ra = fmaxf(a, 0.0f);
    const float rb = fmaxf(b, 0.0f);
#if __has_builtin(__builtin_amdgcn_cvt_pkrtz)
    return __builtin_bit_cast(unsigned, __builtin_amdgcn_cvt_pkrtz(ra, rb));
#else
    return pk2_rn(ra, rb);
#endif
}

__device__ __forceinline__ float2 unpk2(unsigned u)
{
    h2v h = __builtin_bit_cast(h2v, u);
    return make_float2((float)h[0], (float)h[1]);
}

// ---------------------------------------------------------------------------
// Grid 512 x 256. Blocks 0..15: scan (one wave, 32 batches each).
// Blocks 16..511: persistent proj workers on a c-major atomic queue.
// Handoff: xp f16 [g][t][lane][8 words] in ws + per-(g,chunk) release flags.
// Scan step: X(regs) as MFMA C-input -> 2x mfma_f32_32x32x16_f16 ->
// f32 relu + cvt_pkrtz -> 8 semantics-proof half-broadcasts -> next H frags.
// ---------------------------------------------------------------------------
__global__ __launch_bounds__(256, 2) void rnn_mega_kernel(
    const float* __restrict__ seq, const float* __restrict__ Wih,
    const float* __restrict__ Whh, const float* __restrict__ bih,
    const float* __restrict__ bhh, const float* __restrict__ Wfc,
    const float* __restrict__ bfc, float* __restrict__ out,
    char* __restrict__ ws)
{
    int* ready = (int*)(ws + XP_BYTES);              // [g*32 + c], counts to 4
    int* qctr  = (int*)(ws + XP_BYTES + 4096);

    if (blockIdx.x < NGRP) {
        // ============================ SCAN ============================
        if (threadIdx.x >= 64) return;
        const int g = blockIdx.x;
        const int l = threadIdx.x;
        const int p = l >> 5;

        // W_hh f16 A-fragments: row i = l&31, slot (p,e) -> k = 8p+e
        // (wfA covers j = k, wfB covers j = 16+k)
        half8_t wfA, wfB;
        #pragma unroll
        for (int e = 0; e < 8; ++e) {
            wfA[e] = (_Float16)Whh[(l & 31) * HID + 8 * p + e];
            wfB[e] = (_Float16)Whh[(l & 31) * HID + 16 + 8 * p + e];
        }

        i32x4 hAw = {0, 0, 0, 0}, hBw = {0, 0, 0, 0};  // H frags (f16 words)
        f32x16_t Dl;
        #pragma unroll
        for (int r = 0; r < 16; ++r) Dl[r] = 0.0f;

        const char* xpg = ws + (size_t)g * (TLEN * 2048) + (size_t)l * 32;

        // gate chunk 0, prime prefetch for t=0..3
        while (__hip_atomic_load(&ready[g * 32 + 0], __ATOMIC_RELAXED,
                                 __HIP_MEMORY_SCOPE_AGENT) < 4)
            __builtin_amdgcn_s_sleep(2);
        __builtin_amdgcn_fence(__ATOMIC_ACQUIRE, "agent");

        i32x4 P0a = *(const i32x4*)(xpg + 0 * 2048);
        i32x4 P0b = *(const i32x4*)(xpg + 0 * 2048 + 16);
        i32x4 P1a = *(const i32x4*)(xpg + 1 * 2048);
        i32x4 P1b = *(const i32x4*)(xpg + 1 * 2048 + 16);
        i32x4 P2a = *(const i32x4*)(xpg + 2 * 2048);
        i32x4 P2b = *(const i32x4*)(xpg + 2 * 2048 + 16);
        i32x4 P3a = *(const i32x4*)(xpg + 3 * 2048);
        i32x4 P3b = *(const i32x4*)(xpg + 3 * 2048 + 16);

        __builtin_amdgcn_s_setprio(1);

#define STEP(PA, PB, T)                                                       \
        {                                                                     \
            f32x16_t Cv;                                                      \
            float2 f;                                                         \
            f = unpk2((unsigned)PA[0]); Cv[0]  = f.x; Cv[1]  = f.y;           \
            f = unpk2((unsigned)PA[1]); Cv[2]  = f.x; Cv[3]  = f.y;           \
            f = unpk2((unsigned)PA[2]); Cv[4]  = f.x; Cv[5]  = f.y;           \
            f = unpk2((unsigned)PA[3]); Cv[6]  = f.x; Cv[7]  = f.y;           \
            f = unpk2((unsigned)PB[0]); Cv[8]  = f.x; Cv[9]  = f.y;           \
            f = unpk2((unsigned)PB[1]); Cv[10] = f.x; Cv[11] = f.y;           \
            f = unpk2((unsigned)PB[2]); Cv[12] = f.x; Cv[13] = f.y;           \
            f = unpk2((unsigned)PB[3]); Cv[14] = f.x; Cv[15] = f.y;           \
            if ((T) + 4 < TLEN) {                                             \
                PA = *(const i32x4*)(xpg + ((size_t)((T) + 4)) * 2048);       \
                PB = *(const i32x4*)(xpg + ((size_t)((T) + 4)) * 2048 + 16);  \
            }                                                                 \
            f32x16_t U = __builtin_amdgcn_mfma_f32_32x32x16_f16(              \
                wfB, __builtin_bit_cast(half8_t, hBw), Cv, 0, 0, 0);          \
            Dl = __builtin_amdgcn_mfma_f32_32x32x16_f16(                      \
                wfA, __builtin_bit_cast(half8_t, hAw), U, 0, 0, 0);           \
            const int w0 = (int)cvt_relu_pk(Dl[0],  Dl[1]);                   \
            const int w1 = (int)cvt_relu_pk(Dl[2],  Dl[3]);                   \
            const int w2 = (int)cvt_relu_pk(Dl[4],  Dl[5]);                   \
            const int w3 = (int)cvt_relu_pk(Dl[6],  Dl[7]);                   \
            const int w4 = (int)cvt_relu_pk(Dl[8],  Dl[9]);                   \
            const int w5 = (int)cvt_relu_pk(Dl[10], Dl[11]);                  \
            const int w6 = (int)cvt_relu_pk(Dl[12], Dl[13]);                  \
            const int w7 = (int)cvt_relu_pk(Dl[14], Dl[15]);                  \
            /* cross-half moves via semantics-proof broadcasts */             \
            const int b02 = bhalf(w2, p, 0);   /* p0's w2 -> p1 */            \
            const int b03 = bhalf(w3, p, 0);                                  \
            const int b10 = bhalf(w0, p, 1);   /* p1's w0 -> p0 */            \
            const int b11 = bhalf(w1, p, 1);                                  \
            const int b06 = bhalf(w6, p, 0);                                  \
            const int b07 = bhalf(w7, p, 0);                                  \
            const int b14 = bhalf(w4, p, 1);                                  \
            const int b15 = bhalf(w5, p, 1);                                  \
            hAw[0] = p ? b02 : w0;   /* h[8p+0..1] */                         \
            hAw[1] = p ? b03 : w1;   /* h[8p+2..3] */                         \
            hAw[2] = p ? w2  : b10;  /* h[8p+4..5] */                         \
            hAw[3] = p ? w3  : b11;  /* h[8p+6..7] */                         \
            hBw[0] = p ? b06 : w4;   /* h[16+8p+0..1] */                      \
            hBw[1] = p ? b07 : w5;                                            \
            hBw[2] = p ? w6  : b14;                                           \
            hBw[3] = p ? w7  : b15;                                           \
        }

        for (int c = 0; c < NCHK; ++c) {
            const int cn = (c + 1 < NCHK) ? c + 1 : c;
            while (__hip_atomic_load(&ready[g * 32 + cn], __ATOMIC_RELAXED,
                                     __HIP_MEMORY_SCOPE_AGENT) < 4)
                __builtin_amdgcn_s_sleep(2);
            __builtin_amdgcn_fence(__ATOMIC_ACQUIRE, "agent");

            for (int tq = 0; tq < 4; ++tq) {
                const int tb = c * 16 + tq * 4;
                STEP(P0a, P0b, tb + 0)
                STEP(P1a, P1b, tb + 1)
                STEP(P2a, P2b, tb + 2)
                STEP(P3a, P3b, tb + 3)
            }
        }
#undef STEP
        __builtin_amdgcn_s_setprio(0);

        // final h (f32) from last D
        float hr[16];
        #pragma unroll
        for (int r = 0; r < 16; ++r) hr[r] = fmaxf(Dl[r], 0.0f);

        // FC head: lane's 16 channels -> partial, swap-combine, +bias
        float po[8];
        #pragma unroll
        for (int o = 0; o < OUTD; ++o) {
            float s = 0.0f;
            #pragma unroll
            for (int r = 0; r < 16; ++r) {
                const int i = (r & 3) + 8 * (r >> 2) + 4 * p;
                s = fmaf(hr[r], Wfc[o * HID + i], s);
            }
            po[o] = swap32_add(s) + bfc[o];
        }
        if (l < 32) {
            float4 v0 = make_float4(po[0], po[1], po[2], po[3]);
            float4 v1 = make_float4(po[4], po[5], po[6], po[7]);
            float* op = out + (size_t)(g * 32 + l) * OUTD;
            *(float4*)op = v0;
            *(float4*)(op + 4) = v1;
        }
    } else {
        // ============================ PROJ ============================
        __shared__ int s_item;
        const int tid = threadIdx.x;
        const int wv  = tid >> 6;          // wave 0..3 -> t offset
        const int l   = tid & 63;
        const int p   = l >> 5;

        // W_ih split-bf16 A-fragments (row = channel = l&31, k = kb*16+8p+e)
        short8_t whi[8], wlo[8];
        #pragma unroll
        for (int kb = 0; kb < 8; ++kb) {
            const float* wp = Wih + (l & 31) * INCH + kb * 16 + p * 8;
            split8(*(const float4*)wp, *(const float4*)(wp + 4),
                   &whi[kb], &wlo[kb]);
        }
        float biasr[16];
        #pragma unroll
        for (int r = 0; r < 16; ++r) {
            const int i = (r & 3) + 8 * (r >> 2) + 4 * p;
            biasr[r] = bih[i] + bhh[i];
        }

        while (true) {
            if (tid == 0)
                s_item = __hip_atomic_fetch_add(qctr, 1, __ATOMIC_RELAXED,
                                                __HIP_MEMORY_SCOPE_AGENT);
            __syncthreads();
            const int item = s_item;
            if (item >= ITEMS) break;

            const int c   = item >> 6;
            const int g   = (item >> 2) & 15;
            const int sub = item & 3;
            const int t   = c * 16 + sub * 4 + wv;

            const float* sp = seq +
                ((size_t)(g * 32 + (l & 31)) * TLEN + t) * INCH + p * 8;

            f32x16_t acc;
            #pragma unroll
            for (int r = 0; r < 16; ++r) acc[r] = biasr[r];

            #pragma unroll
            for (int kb = 0; kb < 8; ++kb) {
                short8_t shi, slo;
                split8(*(const float4*)(sp + kb * 16),
                       *(const float4*)(sp + kb * 16 + 4), &shi, &slo);
                acc = __builtin_amdgcn_mfma_f32_32x32x16_bf16(whi[kb], shi, acc, 0, 0, 0);
                acc = __builtin_amdgcn_mfma_f32_32x32x16_bf16(whi[kb], slo, acc, 0, 0, 0);
                acc = __builtin_amdgcn_mfma_f32_32x32x16_bf16(wlo[kb], shi, acc, 0, 0, 0);
            }

            // pack f16 RNE, store 32 B per lane (coalesced 2 KB per (g,t))
            i32x4 oa, ob;
            oa[0] = (int)pk2_rn(acc[0],  acc[1]);
            oa[1] = (int)pk2_rn(acc[2],  acc[3]);
            oa[2] = (int)pk2_rn(acc[4],  acc[5]);
            oa[3] = (int)pk2_rn(acc[6],  acc[7]);
            ob[0] = (int)pk2_rn(acc[8],  acc[9]);
            ob[1] = (int)pk2_rn(acc[10], acc[11]);
            ob[2] = (int)pk2_rn(acc[12], acc[13]);
            ob[3] = (int)pk2_rn(acc[14], acc[15]);
            char* dst = ws + ((size_t)(g * TLEN + t) * 64 + l) * 32;
            *(i32x4*)dst = oa;
            *(i32x4*)(dst + 16) = ob;

            __syncthreads();                 // all 4 waves' stores drained
            if (tid == 0)
                __hip_atomic_fetch_add(&ready[g * 32 + c], 1, __ATOMIC_RELEASE,
                                       __HIP_MEMORY_SCOPE_AGENT);
        }
    }
}

extern "C" void kernel_launch(void* const* d_in, const int* in_sizes, int n_in,
                              void* d_out, int out_size, void* d_ws, size_t ws_size,
                              hipStream_t stream) {
    const float* seq = (const float*)d_in[0];
    const float* Wih = (const float*)d_in[1];
    const float* Whh = (const float*)d_in[2];
    const float* bih = (const float*)d_in[3];
    const float* bhh = (const float*)d_in[4];
    const float* Wfc = (const float*)d_in[5];
    const float* bfc = (const float*)d_in[6];

    // zero flags + queue counter (xp region needs no init; flag-gated)
    (void)hipMemsetAsync((char*)d_ws + XP_BYTES, 0, 8192, stream);

    rnn_mega_kernel<<<dim3(512), dim3(256), 0, stream>>>(
        seq, Wih, Whh, bih, bhh, Wfc, bfc, (float*)d_out, (char*)d_ws);
}

// Round 15
// 207.929 us; speedup vs baseline: 1.0256x; 1.0256x over previous
//
#include <hip/hip_runtime.h>

#define HID   32
#define INCH  128
#define OUTD  8
#define BATCH 512
#define TLEN  512
#define NGRP  16                 // 512 batches / 32 per group
#define NCHK  32                 // 32 chunks x 16 timesteps
#define ITEMS 2048               // 32 c x 16 g x 4 sub
#define XP_BYTES (16u * 1024u * 1024u)   // f16 xp: 16*512*64*32 B
#define CHUNK_B (16 * 2048)              // bytes per (g,chunk): 16 t x 2 KB

typedef __attribute__((ext_vector_type(2)))  int    i32x2;
typedef __attribute__((ext_vector_type(4)))  int    i32x4;
typedef __attribute__((ext_vector_type(8)))  short  short8_t;
typedef __attribute__((ext_vector_type(16))) float  f32x16_t;
typedef __attribute__((ext_vector_type(8)))  _Float16 half8_t;
typedef __attribute__((ext_vector_type(2)))  _Float16 h2v;

// Symmetric permlane32 idiom (HW-verified rounds 6/8): r[0]+r[1] = own+partner
__device__ __forceinline__ i32x2 swap32v(int a, int b)
{
#if __has_builtin(__builtin_amdgcn_permlane32_swap)
    return __builtin_amdgcn_permlane32_swap(a, b, false, false);
#else
    const int lane = threadIdx.x & 63;
    int as = __shfl_xor(a, 32, 64), bs = __shfl_xor(b, 32, 64);
    i32x2 r;
    r[0] = (lane < 32) ? bs : a;
    r[1] = (lane < 32) ? b  : as;
    return r;
#endif
}

__device__ __forceinline__ float swap32_add(float p)
{
    i32x2 r = swap32v(__float_as_int(p), __float_as_int(p));
    return __int_as_float(r[0]) + __int_as_float(r[1]);
}

// Broadcast half-`from`'s x to the whole wave (semantics-proof; round 14 ✓)
__device__ __forceinline__ int bhalf(int x, int p, int from)
{
    const int z = (p == from) ? x : 0;
    i32x2 r = swap32v(z, z);
    return r[0] + r[1];
}

// Split fp32 -> bf16 hi (bit-truncate) + bf16 lo (truncated residual).
__device__ __forceinline__ void split8(const float4 f0, const float4 f1,
                                       short8_t* hi, short8_t* lo)
{
    float x[8] = {f0.x, f0.y, f0.z, f0.w, f1.x, f1.y, f1.z, f1.w};
    short8_t h, l;
    #pragma unroll
    for (int e = 0; e < 8; ++e) {
        const unsigned u  = __float_as_uint(x[e]);
        const unsigned hb = u & 0xFFFF0000u;
        h[e] = (short)(u >> 16);
        const float r = x[e] - __uint_as_float(hb);
        l[e] = (short)(__float_as_uint(r) >> 16);
    }
    *hi = h; *lo = l;
}

__device__ __forceinline__ unsigned pk2_rn(float a, float b)
{
    unsigned short ha = __builtin_bit_cast(unsigned short, (_Float16)a);
    unsigned short hb = __builtin_bit_cast(unsigned short, (_Float16)b);
    return (unsigned)ha | ((unsigned)hb << 16);
}

__device__ __forceinline__ unsigned cvt_relu_pk(float a, float b)
{
    const float ra = fmaxf(a, 0.0f);
    const float rb = fmaxf(b, 0.0f);
#if __has_builtin(__builtin_amdgcn_cvt_pkrtz)
    return __builtin_bit_cast(unsigned, __builtin_amdgcn_cvt_pkrtz(ra, rb));
#else
    return pk2_rn(ra, rb);
#endif
}

__device__ __forceinline__ float2 unpk2(unsigned u)
{
    h2v h = __builtin_bit_cast(h2v, u);
    return make_float2((float)h[0], (float)h[1]);
}

// ---------------------------------------------------------------------------
// Grid 512 x 256. Blocks 0..15: scan groups — wave 0 runs the MFMA
// recurrence for 32 batch rows; waves 1..3 are FETCHERS that poll the ready
// flags and bulk-copy xp chunks global->LDS (double-buffered, barrier per
// chunk). The serial chain touches only LDS + VALU/MFMA.
// Blocks 16..511: persistent proj workers on a c-major atomic queue
// (verbatim round 14, numerics HW-verified).
// ---------------------------------------------------------------------------
__global__ __launch_bounds__(256, 2) void rnn_mega_kernel(
    const float* __restrict__ seq, const float* __restrict__ Wih,
    const float* __restrict__ Whh, const float* __restrict__ bih,
    const float* __restrict__ bhh, const float* __restrict__ Wfc,
    const float* __restrict__ bfc, float* __restrict__ out,
    char* __restrict__ ws)
{
    int* ready = (int*)(ws + XP_BYTES);              // [g*32 + c], counts to 4
    int* qctr  = (int*)(ws + XP_BYTES + 4096);

    if (blockIdx.x < NGRP) {
        __shared__ __align__(16) char xl[2][CHUNK_B];   // 64 KB double buffer
        const int g    = blockIdx.x;
        const int wave = threadIdx.x >> 6;
        const int l    = threadIdx.x & 63;
        const int p    = l >> 5;

        if (wave == 0) {
            // ========================= SCAN WAVE =========================
            half8_t wfA, wfB;
            #pragma unroll
            for (int e = 0; e < 8; ++e) {
                wfA[e] = (_Float16)Whh[(l & 31) * HID + 8 * p + e];
                wfB[e] = (_Float16)Whh[(l & 31) * HID + 16 + 8 * p + e];
            }

            i32x4 hAw = {0, 0, 0, 0}, hBw = {0, 0, 0, 0};
            f32x16_t Dl;
            #pragma unroll
            for (int r = 0; r < 16; ++r) Dl[r] = 0.0f;

            __builtin_amdgcn_s_setprio(1);

#define STEP(XA, XB)                                                          \
            {                                                                 \
                f32x16_t Cv;                                                  \
                float2 f;                                                     \
                f = unpk2((unsigned)XA[0]); Cv[0]  = f.x; Cv[1]  = f.y;       \
                f = unpk2((unsigned)XA[1]); Cv[2]  = f.x; Cv[3]  = f.y;       \
                f = unpk2((unsigned)XA[2]); Cv[4]  = f.x; Cv[5]  = f.y;       \
                f = unpk2((unsigned)XA[3]); Cv[6]  = f.x; Cv[7]  = f.y;       \
                f = unpk2((unsigned)XB[0]); Cv[8]  = f.x; Cv[9]  = f.y;       \
                f = unpk2((unsigned)XB[1]); Cv[10] = f.x; Cv[11] = f.y;       \
                f = unpk2((unsigned)XB[2]); Cv[12] = f.x; Cv[13] = f.y;       \
                f = unpk2((unsigned)XB[3]); Cv[14] = f.x; Cv[15] = f.y;       \
                f32x16_t U = __builtin_amdgcn_mfma_f32_32x32x16_f16(          \
                    wfB, __builtin_bit_cast(half8_t, hBw), Cv, 0, 0, 0);      \
                Dl = __builtin_amdgcn_mfma_f32_32x32x16_f16(                  \
                    wfA, __builtin_bit_cast(half8_t, hAw), U, 0, 0, 0);       \
                const int w0 = (int)cvt_relu_pk(Dl[0],  Dl[1]);               \
                const int w1 = (int)cvt_relu_pk(Dl[2],  Dl[3]);               \
                const int w2 = (int)cvt_relu_pk(Dl[4],  Dl[5]);               \
                const int w3 = (int)cvt_relu_pk(Dl[6],  Dl[7]);               \
                const int w4 = (int)cvt_relu_pk(Dl[8],  Dl[9]);               \
                const int w5 = (int)cvt_relu_pk(Dl[10], Dl[11]);              \
                const int w6 = (int)cvt_relu_pk(Dl[12], Dl[13]);              \
                const int w7 = (int)cvt_relu_pk(Dl[14], Dl[15]);              \
                const int b02 = bhalf(w2, p, 0);                              \
                const int b03 = bhalf(w3, p, 0);                              \
                const int b10 = bhalf(w0, p, 1);                              \
                const int b11 = bhalf(w1, p, 1);                              \
                const int b06 = bhalf(w6, p, 0);                              \
                const int b07 = bhalf(w7, p, 0);                              \
                const int b14 = bhalf(w4, p, 1);                              \
                const int b15 = bhalf(w5, p, 1);                              \
                hAw[0] = p ? b02 : w0;                                        \
                hAw[1] = p ? b03 : w1;                                        \
                hAw[2] = p ? w2  : b10;                                       \
                hAw[3] = p ? w3  : b11;                                       \
                hBw[0] = p ? b06 : w4;                                        \
                hBw[1] = p ? b07 : w5;                                        \
                hBw[2] = p ? w6  : b14;                                       \
                hBw[3] = p ? w7  : b15;                                       \
            }

            for (int c = 0; c < NCHK; ++c) {
                __syncthreads();                        // LDS[c&1] valid
                const char* xb = xl[c & 1] + l * 32;
                i32x4 Xa = *(const i32x4*)(xb);
                i32x4 Xb = *(const i32x4*)(xb + 16);
                #pragma unroll
                for (int tl = 0; tl < 16; ++tl) {
                    i32x4 Na = Xa, Nb = Xb;
                    if (tl < 15) {                      // off-chain prefetch
                        Na = *(const i32x4*)(xb + (tl + 1) * 2048);
                        Nb = *(const i32x4*)(xb + (tl + 1) * 2048 + 16);
                    }
                    STEP(Xa, Xb)
                    Xa = Na; Xb = Nb;
                }
            }
#undef STEP
            __builtin_amdgcn_s_setprio(0);

            float hr[16];
            #pragma unroll
            for (int r = 0; r < 16; ++r) hr[r] = fmaxf(Dl[r], 0.0f);

            float po[8];
            #pragma unroll
            for (int o = 0; o < OUTD; ++o) {
                float s = 0.0f;
                #pragma unroll
                for (int r = 0; r < 16; ++r) {
                    const int i = (r & 3) + 8 * (r >> 2) + 4 * p;
                    s = fmaf(hr[r], Wfc[o * HID + i], s);
                }
                po[o] = swap32_add(s) + bfc[o];
            }
            if (l < 32) {
                float4 v0 = make_float4(po[0], po[1], po[2], po[3]);
                float4 v1 = make_float4(po[4], po[5], po[6], po[7]);
                float* op = out + (size_t)(g * 32 + l) * OUTD;
                *(float4*)op = v0;
                *(float4*)(op + 4) = v1;
            }
        } else {
            // ======================== FETCHER WAVES ========================
            const int fl = (wave - 1) * 64 + l;         // 0..191
            const char* gb0 = ws + (size_t)g * (TLEN * 2048);

            // prologue: chunk 0 -> LDS[0]
            while (__hip_atomic_load(&ready[g * 32 + 0], __ATOMIC_RELAXED,
                                     __HIP_MEMORY_SCOPE_AGENT) < 4)
                __builtin_amdgcn_s_sleep(2);
            __builtin_amdgcn_fence(__ATOMIC_ACQUIRE, "agent");
            {
                const char* gb = gb0;
                i32x4 tmp[11];
                #pragma unroll
                for (int k = 0; k < 11; ++k) {
                    const int u = fl + k * 192;
                    if (u < 2048) tmp[k] = *(const i32x4*)(gb + u * 16);
                }
                #pragma unroll
                for (int k = 0; k < 11; ++k) {
                    const int u = fl + k * 192;
                    if (u < 2048) *(i32x4*)(xl[0] + u * 16) = tmp[k];
                }
            }

            for (int c = 0; c < NCHK; ++c) {
                __syncthreads();
                if (c + 1 < NCHK) {
                    while (__hip_atomic_load(&ready[g * 32 + c + 1],
                                             __ATOMIC_RELAXED,
                                             __HIP_MEMORY_SCOPE_AGENT) < 4)
                        __builtin_amdgcn_s_sleep(2);
                    __builtin_amdgcn_fence(__ATOMIC_ACQUIRE, "agent");
                    const char* gb = gb0 + (size_t)(c + 1) * CHUNK_B;
                    char* lb = xl[(c + 1) & 1];
                    i32x4 tmp[11];
                    #pragma unroll
                    for (int k = 0; k < 11; ++k) {
                        const int u = fl + k * 192;
                        if (u < 2048) tmp[k] = *(const i32x4*)(gb + u * 16);
                    }
                    #pragma unroll
                    for (int k = 0; k < 11; ++k) {
                        const int u = fl + k * 192;
                        if (u < 2048) *(i32x4*)(lb + u * 16) = tmp[k];
                    }
                }
            }
        }
    } else {
        // ============================ PROJ ============================
        __shared__ int s_item;
        const int tid = threadIdx.x;
        const int wv  = tid >> 6;          // wave 0..3 -> t offset
        const int l   = tid & 63;
        const int p   = l >> 5;

        short8_t whi[8], wlo[8];
        #pragma unroll
        for (int kb = 0; kb < 8; ++kb) {
            const float* wp = Wih + (l & 31) * INCH + kb * 16 + p * 8;
            split8(*(const float4*)wp, *(const float4*)(wp + 4),
                   &whi[kb], &wlo[kb]);
        }
        float biasr[16];
        #pragma unroll
        for (int r = 0; r < 16; ++r) {
            const int i = (r & 3) + 8 * (r >> 2) + 4 * p;
            biasr[r] = bih[i] + bhh[i];
        }

        while (true) {
            if (tid == 0)
                s_item = __hip_atomic_fetch_add(qctr, 1, __ATOMIC_RELAXED,
                                                __HIP_MEMORY_SCOPE_AGENT);
            __syncthreads();
            const int item = s_item;
            if (item >= ITEMS) break;

            const int c   = item >> 6;
            const int g   = (item >> 2) & 15;
            const int sub = item & 3;
            const int t   = c * 16 + sub * 4 + wv;

            const float* sp = seq +
                ((size_t)(g * 32 + (l & 31)) * TLEN + t) * INCH + p * 8;

            f32x16_t acc;
            #pragma unroll
            for (int r = 0; r < 16; ++r) acc[r] = biasr[r];

            #pragma unroll
            for (int kb = 0; kb < 8; ++kb) {
                short8_t shi, slo;
                split8(*(const float4*)(sp + kb * 16),
                       *(const float4*)(sp + kb * 16 + 4), &shi, &slo);
                acc = __builtin_amdgcn_mfma_f32_32x32x16_bf16(whi[kb], shi, acc, 0, 0, 0);
                acc = __builtin_amdgcn_mfma_f32_32x32x16_bf16(whi[kb], slo, acc, 0, 0, 0);
                acc = __builtin_amdgcn_mfma_f32_32x32x16_bf16(wlo[kb], shi, acc, 0, 0, 0);
            }

            i32x4 oa, ob;
            oa[0] = (int)pk2_rn(acc[0],  acc[1]);
            oa[1] = (int)pk2_rn(acc[2],  acc[3]);
            oa[2] = (int)pk2_rn(acc[4],  acc[5]);
            oa[3] = (int)pk2_rn(acc[6],  acc[7]);
            ob[0] = (int)pk2_rn(acc[8],  acc[9]);
            ob[1] = (int)pk2_rn(acc[10], acc[11]);
            ob[2] = (int)pk2_rn(acc[12], acc[13]);
            ob[3] = (int)pk2_rn(acc[14], acc[15]);
            char* dst = ws + ((size_t)(g * TLEN + t) * 64 + l) * 32;
            *(i32x4*)dst = oa;
            *(i32x4*)(dst + 16) = ob;

            __syncthreads();                 // all 4 waves' stores drained
            if (tid == 0)
                __hip_atomic_fetch_add(&ready[g * 32 + c], 1, __ATOMIC_RELEASE,
                                       __HIP_MEMORY_SCOPE_AGENT);
        }
    }
}

extern "C" void kernel_launch(void* const* d_in, const int* in_sizes, int n_in,
                              void* d_out, int out_size, void* d_ws, size_t ws_size,
                              hipStream_t stream) {
    const float* seq = (const float*)d_in[0];
    const float* Wih = (const float*)d_in[1];
    const float* Whh = (const float*)d_in[2];
    const float* bih = (const float*)d_in[3];
    const float* bhh = (const float*)d_in[4];
    const float* Wfc = (const float*)d_in[5];
    const float* bfc = (const float*)d_in[6];

    // zero flags + queue counter (xp region needs no init; flag-gated)
    (void)hipMemsetAsync((char*)d_ws + XP_BYTES, 0, 8192, stream);

    rnn_mega_kernel<<<dim3(512), dim3(256), 0, stream>>>(
        seq, Wih, Whh, bih, bhh, Wfc, bfc, (float*)d_out, (char*)d_ws);
}

// Round 16
// 205.333 us; speedup vs baseline: 1.0386x; 1.0126x over previous
//
#include <hip/hip_runtime.h>

#define HID   32
#define INCH  128
#define OUTD  8
#define BATCH 512
#define TLEN  512
#define NGRP  16                 // 512 batches / 32 per group
#define NCHK  32                 // 32 chunks x 16 timesteps
#define ITEMS 2048               // 32 c x 16 g x 4 sub (c-major)
#define NPROJ 496                // proj blocks
#define XP_BYTES (16u * 1024u * 1024u)   // f16 xp: 16*512*2048 B
#define CHUNK_B (16 * 2048)              // bytes per (g,chunk): 16 t x 2 KB

typedef __attribute__((ext_vector_type(2)))  int    i32x2;
typedef __attribute__((ext_vector_type(4)))  int    i32x4;
typedef __attribute__((ext_vector_type(8)))  short  short8_t;
typedef __attribute__((ext_vector_type(16))) float  f32x16_t;
typedef __attribute__((ext_vector_type(8)))  _Float16 half8_t;
typedef __attribute__((ext_vector_type(2)))  _Float16 h2v;

// Symmetric permlane32 idiom (HW-verified rounds 6/8/14)
__device__ __forceinline__ i32x2 swap32v(int a, int b)
{
#if __has_builtin(__builtin_amdgcn_permlane32_swap)
    return __builtin_amdgcn_permlane32_swap(a, b, false, false);
#else
    const int lane = threadIdx.x & 63;
    int as = __shfl_xor(a, 32, 64), bs = __shfl_xor(b, 32, 64);
    i32x2 r;
    r[0] = (lane < 32) ? bs : a;
    r[1] = (lane < 32) ? b  : as;
    return r;
#endif
}

__device__ __forceinline__ float swap32_add(float p)
{
    i32x2 r = swap32v(__float_as_int(p), __float_as_int(p));
    return __int_as_float(r[0]) + __int_as_float(r[1]);
}

// Broadcast half-`from`'s x to the whole wave (semantics-proof; round 14 ✓)
__device__ __forceinline__ int bhalf(int x, int p, int from)
{
    const int z = (p == from) ? x : 0;
    i32x2 r = swap32v(z, z);
    return r[0] + r[1];
}

// Split fp32 -> bf16 hi (bit-truncate) + bf16 lo (truncated residual).
__device__ __forceinline__ void split8(const float4 f0, const float4 f1,
                                       short8_t* hi, short8_t* lo)
{
    float x[8] = {f0.x, f0.y, f0.z, f0.w, f1.x, f1.y, f1.z, f1.w};
    short8_t h, l;
    #pragma unroll
    for (int e = 0; e < 8; ++e) {
        const unsigned u  = __float_as_uint(x[e]);
        const unsigned hb = u & 0xFFFF0000u;
        h[e] = (short)(u >> 16);
        const float r = x[e] - __uint_as_float(hb);
        l[e] = (short)(__float_as_uint(r) >> 16);
    }
    *hi = h; *lo = l;
}

__device__ __forceinline__ unsigned pk2_rn(float a, float b)
{
    unsigned short ha = __builtin_bit_cast(unsigned short, (_Float16)a);
    unsigned short hb = __builtin_bit_cast(unsigned short, (_Float16)b);
    return (unsigned)ha | ((unsigned)hb << 16);
}

__device__ __forceinline__ unsigned cvt_relu_pk(float a, float b)
{
    const float ra = fmaxf(a, 0.0f);
    const float rb = fmaxf(b, 0.0f);
#if __has_builtin(__builtin_amdgcn_cvt_pkrtz)
    return __builtin_bit_cast(unsigned, __builtin_amdgcn_cvt_pkrtz(ra, rb));
#else
    return pk2_rn(ra, rb);
#endif
}

__device__ __forceinline__ float2 unpk2(unsigned u)
{
    h2v h = __builtin_bit_cast(h2v, u);
    return make_float2((float)h[0], (float)h[1]);
}

// ---------------------------------------------------------------------------
// Grid 512 x 256. Blocks 0..15: scan groups — wave 0 runs the MFMA
// recurrence (32 batch rows); waves 1..3 fetch xp chunks global->LDS.
// Blocks 16..511: proj workers with STATIC c-major item partition
// (item = pid + k*496) — no queue atomic, no intra-block broadcast.
// xp row layout per (g,t): [0,1024) = all lanes' A-halves (16 B each),
// [1024,2048) = all lanes' B-halves  -> contiguous, conflict-free b128.
// ---------------------------------------------------------------------------
__global__ __launch_bounds__(256, 2) void rnn_mega_kernel(
    const float* __restrict__ seq, const float* __restrict__ Wih,
    const float* __restrict__ Whh, const float* __restrict__ bih,
    const float* __restrict__ bhh, const float* __restrict__ Wfc,
    const float* __restrict__ bfc, float* __restrict__ out,
    char* __restrict__ ws)
{
    int* ready = (int*)(ws + XP_BYTES);              // [g*32 + c], counts to 4

    if (blockIdx.x < NGRP) {
        __shared__ __align__(16) char xl[2][CHUNK_B];   // 64 KB double buffer
        const int g    = blockIdx.x;
        const int wave = threadIdx.x >> 6;
        const int l    = threadIdx.x & 63;
        const int p    = l >> 5;

        if (wave == 0) {
            // ========================= SCAN WAVE =========================
            half8_t wfA, wfB;
            #pragma unroll
            for (int e = 0; e < 8; ++e) {
                wfA[e] = (_Float16)Whh[(l & 31) * HID + 8 * p + e];
                wfB[e] = (_Float16)Whh[(l & 31) * HID + 16 + 8 * p + e];
            }

            i32x4 hAw = {0, 0, 0, 0}, hBw = {0, 0, 0, 0};
            f32x16_t Dl;
            #pragma unroll
            for (int r = 0; r < 16; ++r) Dl[r] = 0.0f;

            __builtin_amdgcn_s_setprio(1);

#define STEP(XA, XB)                                                          \
            {                                                                 \
                f32x16_t Cv;                                                  \
                float2 f;                                                     \
                f = unpk2((unsigned)XA[0]); Cv[0]  = f.x; Cv[1]  = f.y;       \
                f = unpk2((unsigned)XA[1]); Cv[2]  = f.x; Cv[3]  = f.y;       \
                f = unpk2((unsigned)XA[2]); Cv[4]  = f.x; Cv[5]  = f.y;       \
                f = unpk2((unsigned)XA[3]); Cv[6]  = f.x; Cv[7]  = f.y;       \
                f = unpk2((unsigned)XB[0]); Cv[8]  = f.x; Cv[9]  = f.y;       \
                f = unpk2((unsigned)XB[1]); Cv[10] = f.x; Cv[11] = f.y;       \
                f = unpk2((unsigned)XB[2]); Cv[12] = f.x; Cv[13] = f.y;       \
                f = unpk2((unsigned)XB[3]); Cv[14] = f.x; Cv[15] = f.y;       \
                f32x16_t U = __builtin_amdgcn_mfma_f32_32x32x16_f16(          \
                    wfB, __builtin_bit_cast(half8_t, hBw), Cv, 0, 0, 0);      \
                Dl = __builtin_amdgcn_mfma_f32_32x32x16_f16(                  \
                    wfA, __builtin_bit_cast(half8_t, hAw), U, 0, 0, 0);       \
                const int w0 = (int)cvt_relu_pk(Dl[0],  Dl[1]);               \
                const int w1 = (int)cvt_relu_pk(Dl[2],  Dl[3]);               \
                const int w2 = (int)cvt_relu_pk(Dl[4],  Dl[5]);               \
                const int w3 = (int)cvt_relu_pk(Dl[6],  Dl[7]);               \
                const int w4 = (int)cvt_relu_pk(Dl[8],  Dl[9]);               \
                const int w5 = (int)cvt_relu_pk(Dl[10], Dl[11]);              \
                const int w6 = (int)cvt_relu_pk(Dl[12], Dl[13]);              \
                const int w7 = (int)cvt_relu_pk(Dl[14], Dl[15]);              \
                const int b02 = bhalf(w2, p, 0);                              \
                const int b03 = bhalf(w3, p, 0);                              \
                const int b10 = bhalf(w0, p, 1);                              \
                const int b11 = bhalf(w1, p, 1);                              \
                const int b06 = bhalf(w6, p, 0);                              \
                const int b07 = bhalf(w7, p, 0);                              \
                const int b14 = bhalf(w4, p, 1);                              \
                const int b15 = bhalf(w5, p, 1);                              \
                hAw[0] = p ? b02 : w0;                                        \
                hAw[1] = p ? b03 : w1;                                        \
                hAw[2] = p ? w2  : b10;                                       \
                hAw[3] = p ? w3  : b11;                                       \
                hBw[0] = p ? b06 : w4;                                        \
                hBw[1] = p ? b07 : w5;                                        \
                hBw[2] = p ? w6  : b14;                                       \
                hBw[3] = p ? w7  : b15;                                       \
            }

            for (int c = 0; c < NCHK; ++c) {
                __syncthreads();                        // LDS[c&1] valid
                const char* xb = xl[c & 1];
                i32x4 Xa = *(const i32x4*)(xb + l * 16);
                i32x4 Xb = *(const i32x4*)(xb + 1024 + l * 16);
                #pragma unroll
                for (int tl = 0; tl < 16; ++tl) {
                    i32x4 Na = Xa, Nb = Xb;
                    if (tl < 15) {                      // off-chain prefetch
                        Na = *(const i32x4*)(xb + (tl + 1) * 2048 + l * 16);
                        Nb = *(const i32x4*)(xb + (tl + 1) * 2048 + 1024 + l * 16);
                    }
                    STEP(Xa, Xb)
                    Xa = Na; Xb = Nb;
                }
            }
#undef STEP
            __builtin_amdgcn_s_setprio(0);

            float hr[16];
            #pragma unroll
            for (int r = 0; r < 16; ++r) hr[r] = fmaxf(Dl[r], 0.0f);

            float po[8];
            #pragma unroll
            for (int o = 0; o < OUTD; ++o) {
                float s = 0.0f;
                #pragma unroll
                for (int r = 0; r < 16; ++r) {
                    const int i = (r & 3) + 8 * (r >> 2) + 4 * p;
                    s = fmaf(hr[r], Wfc[o * HID + i], s);
                }
                po[o] = swap32_add(s) + bfc[o];
            }
            if (l < 32) {
                float4 v0 = make_float4(po[0], po[1], po[2], po[3]);
                float4 v1 = make_float4(po[4], po[5], po[6], po[7]);
                float* op = out + (size_t)(g * 32 + l) * OUTD;
                *(float4*)op = v0;
                *(float4*)(op + 4) = v1;
            }
        } else {
            // ======================== FETCHER WAVES ========================
            const int fl = (wave - 1) * 64 + l;         // 0..191
            const char* gb0 = ws + (size_t)g * (TLEN * 2048);

            while (__hip_atomic_load(&ready[g * 32 + 0], __ATOMIC_RELAXED,
                                     __HIP_MEMORY_SCOPE_AGENT) < 4)
                __builtin_amdgcn_s_sleep(2);
            __builtin_amdgcn_fence(__ATOMIC_ACQUIRE, "agent");
            {
                i32x4 tmp[11];
                #pragma unroll
                for (int k = 0; k < 11; ++k) {
                    const int u = fl + k * 192;
                    if (u < 2048) tmp[k] = *(const i32x4*)(gb0 + u * 16);
                }
                #pragma unroll
                for (int k = 0; k < 11; ++k) {
                    const int u = fl + k * 192;
                    if (u < 2048) *(i32x4*)(xl[0] + u * 16) = tmp[k];
                }
            }

            for (int c = 0; c < NCHK; ++c) {
                __syncthreads();
                if (c + 1 < NCHK) {
                    while (__hip_atomic_load(&ready[g * 32 + c + 1],
                                             __ATOMIC_RELAXED,
                                             __HIP_MEMORY_SCOPE_AGENT) < 4)
                        __builtin_amdgcn_s_sleep(2);
                    __builtin_amdgcn_fence(__ATOMIC_ACQUIRE, "agent");
                    const char* gb = gb0 + (size_t)(c + 1) * CHUNK_B;
                    char* lb = xl[(c + 1) & 1];
                    i32x4 tmp[11];
                    #pragma unroll
                    for (int k = 0; k < 11; ++k) {
                        const int u = fl + k * 192;
                        if (u < 2048) tmp[k] = *(const i32x4*)(gb + u * 16);
                    }
                    #pragma unroll
                    for (int k = 0; k < 11; ++k) {
                        const int u = fl + k * 192;
                        if (u < 2048) *(i32x4*)(lb + u * 16) = tmp[k];
                    }
                }
            }
        }
    } else {
        // ============================ PROJ ============================
        const int pid = blockIdx.x - NGRP;  // 0..495
        const int tid = threadIdx.x;
        const int wv  = tid >> 6;          // wave 0..3 -> t offset
        const int l   = tid & 63;
        const int p   = l >> 5;

        short8_t whi[8], wlo[8];
        #pragma unroll
        for (int kb = 0; kb < 8; ++kb) {
            const float* wp = Wih + (l & 31) * INCH + kb * 16 + p * 8;
            split8(*(const float4*)wp, *(const float4*)(wp + 4),
                   &whi[kb], &wlo[kb]);
        }
        float biasr[16];
        #pragma unroll
        for (int r = 0; r < 16; ++r) {
            const int i = (r & 3) + 8 * (r >> 2) + 4 * p;
            biasr[r] = bih[i] + bhh[i];
        }

        for (int k = 0; k < 5; ++k) {
            const int item = pid + k * NPROJ;          // static c-major
            if (item >= ITEMS) break;                  // uniform per block

            const int c   = item >> 6;
            const int g   = (item >> 2) & 15;
            const int sub = item & 3;
            const int t   = c * 16 + sub * 4 + wv;

            const float* sp = seq +
                ((size_t)(g * 32 + (l & 31)) * TLEN + t) * INCH + p * 8;

            f32x16_t acc;
            #pragma unroll
            for (int r = 0; r < 16; ++r) acc[r] = biasr[r];

            #pragma unroll
            for (int kb = 0; kb < 8; ++kb) {
                short8_t shi, slo;
                split8(*(const float4*)(sp + kb * 16),
                       *(const float4*)(sp + kb * 16 + 4), &shi, &slo);
                acc = __builtin_amdgcn_mfma_f32_32x32x16_bf16(whi[kb], shi, acc, 0, 0, 0);
                acc = __builtin_amdgcn_mfma_f32_32x32x16_bf16(whi[kb], slo, acc, 0, 0, 0);
                acc = __builtin_amdgcn_mfma_f32_32x32x16_bf16(wlo[kb], shi, acc, 0, 0, 0);
            }

            i32x4 oa, ob;
            oa[0] = (int)pk2_rn(acc[0],  acc[1]);
            oa[1] = (int)pk2_rn(acc[2],  acc[3]);
            oa[2] = (int)pk2_rn(acc[4],  acc[5]);
            oa[3] = (int)pk2_rn(acc[6],  acc[7]);
            ob[0] = (int)pk2_rn(acc[8],  acc[9]);
            ob[1] = (int)pk2_rn(acc[10], acc[11]);
            ob[2] = (int)pk2_rn(acc[12], acc[13]);
            ob[3] = (int)pk2_rn(acc[14], acc[15]);
            char* rowb = ws + (size_t)(g * TLEN + t) * 2048;
            *(i32x4*)(rowb + l * 16) = oa;             // A-halves [0,1024)
            *(i32x4*)(rowb + 1024 + l * 16) = ob;      // B-halves [1024,2048)

            __syncthreads();                 // drains vmcnt before release
            if (tid == 0)
                __hip_atomic_fetch_add(&ready[g * 32 + c], 1, __ATOMIC_RELEASE,
                                       __HIP_MEMORY_SCOPE_AGENT);
        }
    }
}

extern "C" void kernel_launch(void* const* d_in, const int* in_sizes, int n_in,
                              void* d_out, int out_size, void* d_ws, size_t ws_size,
                              hipStream_t stream) {
    const float* seq = (const float*)d_in[0];
    const float* Wih = (const float*)d_in[1];
    const float* Whh = (const float*)d_in[2];
    const float* bih = (const float*)d_in[3];
    const float* bhh = (const float*)d_in[4];
    const float* Wfc = (const float*)d_in[5];
    const float* bfc = (const float*)d_in[6];

    // zero the ready flags (xp region needs no init; flag-gated)
    (void)hipMemsetAsync((char*)d_ws + XP_BYTES, 0, 8192, stream);

    rnn_mega_kernel<<<dim3(512), dim3(256), 0, stream>>>(
        seq, Wih, Whh, bih, bhh, Wfc, bfc, (float*)d_out, (char*)d_ws);
}